// Round 5
// baseline (406.133 us; speedup 1.0000x reference)
//
#include <hip/hip_runtime.h>
#include <hip/hip_bf16.h>
#include <stdint.h>

// Self-attention (no softmax) via matmul reassociation.
// R4: xt_build rebuilt with 256-wide n-tiles (512B-contiguous xT writes; R2
//     showed the old 128B-chunk pattern caps at 2.5 TB/s); MT gemm unsplit
//     (single gemm_bt, scale fused) — drops reduce2 + 1 dispatch + 32 MiB
//     partials.
//   cvt_all : x fp32 -> x_bf bf16 + all weights
//   xt_build: x_bf -> xT (transpose per batch, L3-hot src) [8,1024,4096]
//   gemm_qk : Th = x@Wt^T [32768,256] AND PhT = (x@Wp^T)^T [256,32768]
//   Rt      = PhT x xT^T (bt, K=4096 split-8)        [8,256,1024]
//   MT      = scale*Wg x Rt^T (bt, K=1024, unsplit)  [8,1024,256]
//   out     = Th x MT^T (bt, K=256, fp32 out)        [8,4096,1024]
// d_out doubles as scratch: xT [0,64MiB), RtP [64,128MiB).

typedef __attribute__((ext_vector_type(8))) short bf16x8;
typedef __attribute__((ext_vector_type(4))) float f32x4;

__device__ inline unsigned short f32_to_bf16_rne(float f) {
  union { float f; uint32_t u; } v; v.f = f;
  uint32_t r = v.u + 0x7fffu + ((v.u >> 16) & 1u);
  return (unsigned short)(r >> 16);
}

__device__ inline void gload_lds16(const void* g, void* lds) {
  __builtin_amdgcn_global_load_lds(
      (const __attribute__((address_space(1))) void*)g,
      (__attribute__((address_space(3))) void*)lds, 16, 0, 0);
}

// XCD-aware bijective remap of the flattened grid (requires total%8==0).
__device__ inline void xcd_swizzle(int& bx, int& by, int& bz) {
  int gx = gridDim.x, gy = gridDim.y;
  int total = gx * gy * gridDim.z;
  int lid = blockIdx.x + gx * (blockIdx.y + gy * blockIdx.z);
  int cpx = total >> 3;
  int swz = (lid & 7) * cpx + (lid >> 3);
  bx = swz % gx;
  int t = swz / gx;
  by = t % gy;
  bz = t / gy;
}

// ------- x fp32 -> x_bf bf16 (blocks 0..2047) + weights (blocks 2048..3583) --
__global__ __launch_bounds__(256) void cvt_all(
    const float* __restrict__ x, const float* __restrict__ Wt,
    const float* __restrict__ Wp, const float* __restrict__ Wg,
    unsigned short* __restrict__ x_bf, unsigned short* __restrict__ Wtb,
    unsigned short* __restrict__ Wpb, unsigned short* __restrict__ Wgb) {
  int bid = blockIdx.x;
  if (bid < 2048) {
    long long idx = (long long)bid * 256 + threadIdx.x;
    const long long stride = 2048LL * 256LL;
#pragma unroll 2
    for (long long i = idx; i < 4194304LL; i += stride) {
      float4 a = ((const float4*)x)[i * 2];
      float4 b = ((const float4*)x)[i * 2 + 1];
      bf16x8 o;
      o[0] = (short)f32_to_bf16_rne(a.x);
      o[1] = (short)f32_to_bf16_rne(a.y);
      o[2] = (short)f32_to_bf16_rne(a.z);
      o[3] = (short)f32_to_bf16_rne(a.w);
      o[4] = (short)f32_to_bf16_rne(b.x);
      o[5] = (short)f32_to_bf16_rne(b.y);
      o[6] = (short)f32_to_bf16_rne(b.z);
      o[7] = (short)f32_to_bf16_rne(b.w);
      ((bf16x8*)x_bf)[i] = o;
    }
  } else {
    int i = (bid - 2048) * 256 + threadIdx.x;  // float4 index, total 393216
    const float* src;
    unsigned short* dst;
    int off;
    if (i < 65536) { src = Wt; dst = Wtb; off = i; }
    else if (i < 131072) { src = Wp; dst = Wpb; off = i - 65536; }
    else { src = Wg; dst = Wgb; off = i - 131072; }
    float4 v = ((const float4*)src)[off];
    ushort4 o;
    o.x = f32_to_bf16_rne(v.x);
    o.y = f32_to_bf16_rne(v.y);
    o.z = f32_to_bf16_rne(v.z);
    o.w = f32_to_bf16_rne(v.w);
    ((ushort4*)dst)[off] = o;
  }
}

// ------------- transpose x_bf -> xT, 256n x 64f tile through LDS -----------
// xT writes: 512 B contiguous per f-row (32 lanes x 16B). x_bf reads are
// 128 B chunks but L3-hot. LDS [n][f] with f XOR-swizzle ((n>>3)&7)*8:
// ushort4 writes stay 8B-aligned; phase-2 b16 reads spread across banks.
__global__ __launch_bounds__(256) void xt_build(
    const unsigned short* __restrict__ x_bf, unsigned short* __restrict__ xT) {
  __shared__ unsigned short tile[256 * 64];
  const int tid = threadIdx.x;
  const int n0 = blockIdx.x * 256;
  const int f0 = blockIdx.y * 64;
  const long long b = blockIdx.z;
  const unsigned short* xb = x_bf + b * 4194304LL;
  unsigned short* xTb = xT + b * 4194304LL;

  {  // phase 1: bf16x8 read along f, 2x ushort4 swizzled LDS writes
    const int r  = tid >> 3;         // 0..31
    const int c8 = (tid & 7) * 8;    // 0..56
#pragma unroll
    for (int rr = 0; rr < 8; ++rr) {
      int n = rr * 32 + r;
      bf16x8 v = *(const bf16x8*)&xb[(long long)(n0 + n) * 1024 + f0 + c8];
      int s = ((n >> 3) & 7) * 8;
      ushort4 lo, hi;
      lo.x = (unsigned short)v[0]; lo.y = (unsigned short)v[1];
      lo.z = (unsigned short)v[2]; lo.w = (unsigned short)v[3];
      hi.x = (unsigned short)v[4]; hi.y = (unsigned short)v[5];
      hi.z = (unsigned short)v[6]; hi.w = (unsigned short)v[7];
      *(ushort4*)&tile[n * 64 + (c8 ^ s)]       = lo;
      *(ushort4*)&tile[n * 64 + ((c8 + 4) ^ s)] = hi;
    }
  }
  __syncthreads();
  {  // phase 2: gather 8 n per (f, nc) task, 16B coalesced store to xT
    const int g  = tid & 31;
    const int nc = g * 8;
    const int fb = tid >> 5;         // 0..7
    const int s  = (g & 7) * 8;      // ((nc+e)>>3)&7 == g&7 for e<8
#pragma unroll
    for (int it = 0; it < 8; ++it) {
      int f = it * 8 + fb;
      bf16x8 v;
#pragma unroll
      for (int e = 0; e < 8; ++e) {
        v[e] = (short)tile[(nc + e) * 64 + (f ^ s)];
      }
      *(bf16x8*)&xTb[(long long)(f0 + f) * 4096 + n0 + nc] = v;
    }
  }
}

// ---- fused theta+phi gemm: one pass over x_bf, combined weights [512,1024] -
// grid (4,256): bx<2 -> Th[n,l] (normal);  bx>=2 -> PhT[l,n] via swapped-
// operand MFMA (first operand supplies C rows), coalesced along n.
__global__ __launch_bounds__(256) void gemm_qk(
    const unsigned short* __restrict__ X, const unsigned short* __restrict__ W,
    unsigned short* __restrict__ Th, unsigned short* __restrict__ PhT) {
  __shared__ unsigned short As[128 * 32];
  __shared__ unsigned short Bs[128 * 32];

  const int tid  = threadIdx.x;
  const int lane = tid & 63;
  const int wave = tid >> 6;
  int bx, by, bz;
  xcd_swizzle(bx, by, bz);
  (void)bz;
  const int m0 = by * 128;   // x rows
  const int n0 = bx * 128;   // combined weight rows (0..511)

  const int sub = lane >> 2;
  const int kk  = (lane & 3) * 8;
  const int wm = (wave >> 1) * 64;
  const int wn = (wave & 1) * 64;
  const int li = lane & 15;
  const int q  = lane >> 4;

  f32x4 acc[4][4] = {};

  for (int k0 = 0; k0 < 1024; k0 += 32) {
#pragma unroll
    for (int r = 0; r < 2; ++r) {
      int chunk = r * 4 + wave;
      int row = chunk * 16 + sub;
      gload_lds16(X + (long long)(m0 + row) * 1024 + k0 + kk, (char*)As + chunk * 1024);
      gload_lds16(W + (long long)(n0 + row) * 1024 + k0 + kk, (char*)Bs + chunk * 1024);
    }
    __syncthreads();
    bf16x8 af[4], bfr[4];
#pragma unroll
    for (int i = 0; i < 4; ++i) {
      af[i]  = *(const bf16x8*)&As[(wm + i * 16 + li) * 32 + q * 8];
      bfr[i] = *(const bf16x8*)&Bs[(wn + i * 16 + li) * 32 + q * 8];
    }
    if (bx < 2) {
#pragma unroll
      for (int i = 0; i < 4; ++i)
#pragma unroll
        for (int j = 0; j < 4; ++j)
          acc[i][j] = __builtin_amdgcn_mfma_f32_16x16x32_bf16(af[i], bfr[j], acc[i][j], 0, 0, 0);
    } else {
#pragma unroll
      for (int i = 0; i < 4; ++i)
#pragma unroll
        for (int j = 0; j < 4; ++j)
          acc[i][j] = __builtin_amdgcn_mfma_f32_16x16x32_bf16(bfr[i], af[j], acc[i][j], 0, 0, 0);
    }
    __syncthreads();
  }

  if (bx < 2) {
#pragma unroll
    for (int i = 0; i < 4; ++i)
#pragma unroll
      for (int j = 0; j < 4; ++j)
#pragma unroll
        for (int r = 0; r < 4; ++r) {
          int row = m0 + wm + i * 16 + q * 4 + r;       // n
          int col = n0 + wn + j * 16 + li;              // l (0..255)
          Th[(long long)row * 256 + col] = f32_to_bf16_rne(acc[i][j][r]);
        }
  } else {
    const int l0 = n0 - 256;
#pragma unroll
    for (int i = 0; i < 4; ++i)
#pragma unroll
      for (int j = 0; j < 4; ++j)
#pragma unroll
        for (int r = 0; r < 4; ++r) {
          int row = l0 + wn + i * 16 + q * 4 + r;       // l (0..255)
          int col = m0 + wm + j * 16 + li;              // n
          PhT[(long long)row * 32768 + col] = f32_to_bf16_rne(acc[i][j][r]);
        }
  }
}

// ---------------- C[M,N] = scale * A[M,K] @ B[N,K]^T (both K-contiguous) ----
template <bool OUT_F32>
__global__ __launch_bounds__(256) void gemm_bt(
    const unsigned short* __restrict__ A, const unsigned short* __restrict__ B,
    void* __restrict__ Cv,
    int K, int lda, int ldb, int ldc,
    long long sA, long long sB, long long sC, float scale) {
  __shared__ unsigned short As[128 * 32];
  __shared__ unsigned short Bs[128 * 32];

  const int tid  = threadIdx.x;
  const int lane = tid & 63;
  const int wave = tid >> 6;
  int bx, by, bz;
  xcd_swizzle(bx, by, bz);
  const int m0 = by * 128;
  const int n0 = bx * 128;
  const int z  = bz;

  A += (long long)z * sA;
  B += (long long)z * sB;

  const int sub = lane >> 2;
  const int kk  = (lane & 3) * 8;
  const int wm = (wave >> 1) * 64;
  const int wn = (wave & 1) * 64;
  const int li = lane & 15;
  const int q  = lane >> 4;

  f32x4 acc[4][4] = {};

  for (int k0 = 0; k0 < K; k0 += 32) {
#pragma unroll
    for (int r = 0; r < 2; ++r) {
      int chunk = r * 4 + wave;
      int row = chunk * 16 + sub;
      gload_lds16(A + (long long)(m0 + row) * lda + k0 + kk, (char*)As + chunk * 1024);
      gload_lds16(B + (long long)(n0 + row) * ldb + k0 + kk, (char*)Bs + chunk * 1024);
    }
    __syncthreads();
    bf16x8 af[4], bfr[4];
#pragma unroll
    for (int i = 0; i < 4; ++i) {
      af[i]  = *(const bf16x8*)&As[(wm + i * 16 + li) * 32 + q * 8];
      bfr[i] = *(const bf16x8*)&Bs[(wn + i * 16 + li) * 32 + q * 8];
    }
#pragma unroll
    for (int i = 0; i < 4; ++i)
#pragma unroll
      for (int j = 0; j < 4; ++j)
        acc[i][j] = __builtin_amdgcn_mfma_f32_16x16x32_bf16(af[i], bfr[j], acc[i][j], 0, 0, 0);
    __syncthreads();
  }

  if (OUT_F32) {
    float* C = (float*)Cv + (long long)z * sC;
#pragma unroll
    for (int i = 0; i < 4; ++i)
#pragma unroll
      for (int j = 0; j < 4; ++j)
#pragma unroll
        for (int r = 0; r < 4; ++r) {
          int row = m0 + wm + i * 16 + q * 4 + r;
          int col = n0 + wn + j * 16 + li;
          C[(long long)row * ldc + col] = acc[i][j][r] * scale;
        }
  } else {
    unsigned short* C = (unsigned short*)Cv + (long long)z * sC;
#pragma unroll
    for (int i = 0; i < 4; ++i)
#pragma unroll
      for (int j = 0; j < 4; ++j)
#pragma unroll
        for (int r = 0; r < 4; ++r) {
          int row = m0 + wm + i * 16 + q * 4 + r;
          int col = n0 + wn + j * 16 + li;
          C[(long long)row * ldc + col] = f32_to_bf16_rne(acc[i][j][r] * scale);
        }
  }
}

// ------------- split-K variant: fp32 partials, z = batch*nsplit + split -----
__global__ __launch_bounds__(256) void gemm_bt_split(
    const unsigned short* __restrict__ A, const unsigned short* __restrict__ B,
    float* __restrict__ Cp,
    int Ks, int lda, int ldb, int ldc,
    long long sA, long long sB, long long sC, int nsplit) {
  __shared__ unsigned short As[128 * 32];
  __shared__ unsigned short Bs[128 * 32];

  const int tid  = threadIdx.x;
  const int lane = tid & 63;
  const int wave = tid >> 6;
  int bx, by, bz;
  xcd_swizzle(bx, by, bz);
  const int m0 = by * 128;
  const int n0 = bx * 128;
  const int z  = bz;
  const int batch = z / nsplit;
  const int split = z - batch * nsplit;

  A += batch * sA + (long long)split * Ks;   // k-contiguous: split offsets along k
  B += batch * sB + (long long)split * Ks;
  Cp += (long long)z * sC;

  const int sub = lane >> 2;
  const int kk  = (lane & 3) * 8;
  const int wm = (wave >> 1) * 64;
  const int wn = (wave & 1) * 64;
  const int li = lane & 15;
  const int q  = lane >> 4;

  f32x4 acc[4][4] = {};

  for (int k0 = 0; k0 < Ks; k0 += 32) {
#pragma unroll
    for (int r = 0; r < 2; ++r) {
      int chunk = r * 4 + wave;
      int row = chunk * 16 + sub;
      gload_lds16(A + (long long)(m0 + row) * lda + k0 + kk, (char*)As + chunk * 1024);
      gload_lds16(B + (long long)(n0 + row) * ldb + k0 + kk, (char*)Bs + chunk * 1024);
    }
    __syncthreads();
    bf16x8 af[4], bfr[4];
#pragma unroll
    for (int i = 0; i < 4; ++i) {
      af[i]  = *(const bf16x8*)&As[(wm + i * 16 + li) * 32 + q * 8];
      bfr[i] = *(const bf16x8*)&Bs[(wn + i * 16 + li) * 32 + q * 8];
    }
#pragma unroll
    for (int i = 0; i < 4; ++i)
#pragma unroll
      for (int j = 0; j < 4; ++j)
        acc[i][j] = __builtin_amdgcn_mfma_f32_16x16x32_bf16(af[i], bfr[j], acc[i][j], 0, 0, 0);
    __syncthreads();
  }

#pragma unroll
  for (int i = 0; i < 4; ++i)
#pragma unroll
    for (int j = 0; j < 4; ++j)
#pragma unroll
      for (int r = 0; r < 4; ++r) {
        int row = m0 + wm + i * 16 + q * 4 + r;
        int col = n0 + wn + j * 16 + li;
        Cp[(long long)row * ldc + col] = acc[i][j][r];
      }
}

// ---- sum nsplit fp32 slices (each 262144 els per batch-slice) -> bf16 -----
__global__ __launch_bounds__(256) void reduce_splits(
    const float* __restrict__ P, unsigned short* __restrict__ O,
    int nsplit, float scale) {
  int i = (blockIdx.x * 256 + threadIdx.x) * 4;
  int batch = i >> 18;          // / 262144
  int j = i & 262143;
  const float* p = P + (long long)batch * nsplit * 262144 + j;
  float4 s = *(const float4*)p;
  for (int t = 1; t < nsplit; ++t) {
    float4 v = *(const float4*)(p + (long long)t * 262144);
    s.x += v.x; s.y += v.y; s.z += v.z; s.w += v.w;
  }
  ushort4 o;
  o.x = f32_to_bf16_rne(s.x * scale);
  o.y = f32_to_bf16_rne(s.y * scale);
  o.z = f32_to_bf16_rne(s.z * scale);
  o.w = f32_to_bf16_rne(s.w * scale);
  ((ushort4*)O)[i >> 2] = o;
}

// ---------------------------------------------------------------------------
extern "C" void kernel_launch(void* const* d_in, const int* in_sizes, int n_in,
                              void* d_out, int out_size, void* d_ws, size_t ws_size,
                              hipStream_t stream) {
  const float* x  = (const float*)d_in[0];   // [8,4096,1024]
  const float* Wt = (const float*)d_in[1];   // [256,1024]
  const float* Wp = (const float*)d_in[2];   // [256,1024]
  const float* Wg = (const float*)d_in[3];   // [1024,1024]
  float* out = (float*)d_out;                // [8,4096,1024] fp32 (128 MiB)

  // ws layout (<= 112,197,632 B proven):
  char* ws = (char*)d_ws;
  unsigned short* x_bf = (unsigned short*)(ws);               // 64 MB [32768,1024]
  unsigned short* Th   = (unsigned short*)(ws + 67108864);    // 16 MB theta [32768,256]
  unsigned short* PhT  = (unsigned short*)(ws + 83886080);    // 16 MB phiT [256,32768]
  unsigned short* Rt   = (unsigned short*)(ws + 100663296);   //  4 MB [8,256,1024]
  unsigned short* MT   = (unsigned short*)(ws + 104857600);   //  4 MB [8,1024,256]
  unsigned short* Wtb  = (unsigned short*)(ws + 109051904);   // 512 KB
  unsigned short* Wpb  = (unsigned short*)(ws + 109576192);   // 512 KB (contiguous after Wtb)
  unsigned short* Wgb  = (unsigned short*)(ws + 110100480);   //   2 MB

  // d_out as scratch until final gemm overwrites it:
  unsigned short* xT = (unsigned short*)d_out;              // [0,64MiB) [8,1024,4096]
  float* RtP = (float*)((char*)d_out + 67108864);           // [64,128MiB): 8 splits x 8 MiB

  cvt_all<<<dim3(3584), 256, 0, stream>>>(x, Wt, Wp, Wg, x_bf, Wtb, Wpb, Wgb);
  xt_build<<<dim3(16, 16, 8), 256, 0, stream>>>(x_bf, xT);

  // Th = x@Wt^T [32768,256] and PhT = (x@Wp^T)^T [256,32768]; W = [Wtb;Wpb]
  gemm_qk<<<dim3(4, 256, 1), 256, 0, stream>>>(x_bf, Wtb, Th, PhT);

  // Rt[b] = PhT_b @ xT_b^T : M=256 N=1024 K=4096, split-8 (Ks=512), 1024 blk
  gemm_bt_split<<<dim3(8, 2, 64), 256, 0, stream>>>(
      PhT, xT, RtP, 512, 32768, 4096, 1024,
      4096LL, 4194304LL, 262144LL, 8);
  reduce_splits<<<dim3(2048), 256, 0, stream>>>(RtP, Rt, 8, 1.0f);

  // MT[b] = scale * Wg @ Rt_b^T : M=1024 N=256 K=1024, unsplit, 128 blk
  gemm_bt<false><<<dim3(2, 8, 8), 256, 0, stream>>>(
      Wgb, Rt, MT, 1024, 1024, 1024, 256,
      0LL, 262144LL, 262144LL, 0.03125f);

  // out[b] = Th_b @ MT_b^T : M=4096 N=1024 K=256, fp32 out
  gemm_bt<true><<<dim3(8, 32, 8), 256, 0, stream>>>(
      Th, MT, out, 256, 256, 256, 1024,
      1048576LL, 262144LL, 4194304LL, 1.0f);
}

// Round 6
// 404.835 us; speedup vs baseline: 1.0032x; 1.0032x over previous
//
#include <hip/hip_runtime.h>
#include <hip/hip_bf16.h>
#include <stdint.h>

// Self-attention (no softmax) via matmul reassociation.
// R5: xt_build v3 — 256n x 64f tile, LDS [f][n] xor-swizzled: phase-1 scalar
//     b16 writes (bank-verified conflict-free), phase-2 b128 reads + 512B-
//     contiguous xT row writes. Fixes both R2's 128B-chunk write pattern AND
//     R4's scalar-gather LDS regression. MT stays unsplit (saves dispatch +
//     32 MiB partials).
//   cvt_all : x fp32 -> x_bf bf16 + all weights
//   xt_build: x_bf -> xT (transpose per batch, L3-hot src) [8,1024,4096]
//   gemm_qk : Th = x@Wt^T [32768,256] AND PhT = (x@Wp^T)^T [256,32768]
//   Rt      = PhT x xT^T (bt, K=4096 split-8)        [8,256,1024]
//   MT      = scale*Wg x Rt^T (bt, K=1024, unsplit)  [8,1024,256]
//   out     = Th x MT^T (bt, K=256, fp32 out)        [8,4096,1024]
// d_out doubles as scratch: xT [0,64MiB), RtP [64,128MiB).

typedef __attribute__((ext_vector_type(8))) short bf16x8;
typedef __attribute__((ext_vector_type(4))) float f32x4;

__device__ inline unsigned short f32_to_bf16_rne(float f) {
  union { float f; uint32_t u; } v; v.f = f;
  uint32_t r = v.u + 0x7fffu + ((v.u >> 16) & 1u);
  return (unsigned short)(r >> 16);
}

__device__ inline void gload_lds16(const void* g, void* lds) {
  __builtin_amdgcn_global_load_lds(
      (const __attribute__((address_space(1))) void*)g,
      (__attribute__((address_space(3))) void*)lds, 16, 0, 0);
}

// XCD-aware bijective remap of the flattened grid (requires total%8==0).
__device__ inline void xcd_swizzle(int& bx, int& by, int& bz) {
  int gx = gridDim.x, gy = gridDim.y;
  int total = gx * gy * gridDim.z;
  int lid = blockIdx.x + gx * (blockIdx.y + gy * blockIdx.z);
  int cpx = total >> 3;
  int swz = (lid & 7) * cpx + (lid >> 3);
  bx = swz % gx;
  int t = swz / gx;
  by = t % gy;
  bz = t / gy;
}

// ------- x fp32 -> x_bf bf16 (blocks 0..2047) + weights (blocks 2048..3583) --
__global__ __launch_bounds__(256) void cvt_all(
    const float* __restrict__ x, const float* __restrict__ Wt,
    const float* __restrict__ Wp, const float* __restrict__ Wg,
    unsigned short* __restrict__ x_bf, unsigned short* __restrict__ Wtb,
    unsigned short* __restrict__ Wpb, unsigned short* __restrict__ Wgb) {
  int bid = blockIdx.x;
  if (bid < 2048) {
    long long idx = (long long)bid * 256 + threadIdx.x;
    const long long stride = 2048LL * 256LL;
#pragma unroll 2
    for (long long i = idx; i < 4194304LL; i += stride) {
      float4 a = ((const float4*)x)[i * 2];
      float4 b = ((const float4*)x)[i * 2 + 1];
      bf16x8 o;
      o[0] = (short)f32_to_bf16_rne(a.x);
      o[1] = (short)f32_to_bf16_rne(a.y);
      o[2] = (short)f32_to_bf16_rne(a.z);
      o[3] = (short)f32_to_bf16_rne(a.w);
      o[4] = (short)f32_to_bf16_rne(b.x);
      o[5] = (short)f32_to_bf16_rne(b.y);
      o[6] = (short)f32_to_bf16_rne(b.z);
      o[7] = (short)f32_to_bf16_rne(b.w);
      ((bf16x8*)x_bf)[i] = o;
    }
  } else {
    int i = (bid - 2048) * 256 + threadIdx.x;  // float4 index, total 393216
    const float* src;
    unsigned short* dst;
    int off;
    if (i < 65536) { src = Wt; dst = Wtb; off = i; }
    else if (i < 131072) { src = Wp; dst = Wpb; off = i - 65536; }
    else { src = Wg; dst = Wgb; off = i - 131072; }
    float4 v = ((const float4*)src)[off];
    ushort4 o;
    o.x = f32_to_bf16_rne(v.x);
    o.y = f32_to_bf16_rne(v.y);
    o.z = f32_to_bf16_rne(v.z);
    o.w = f32_to_bf16_rne(v.w);
    ((ushort4*)dst)[off] = o;
  }
}

// ------------- transpose x_bf -> xT, 256n x 64f tile through LDS -----------
// LDS tile[f][n] (64x256) with n-swizzle n ^ s(f), s(f)=((f>>3)&7)*8.
// Phase 1: bf16x8 read along f, 8 scalar b16 LDS writes (verified: all 32
// banks, 2 lanes each -> conflict-free). Phase 2: ds_read_b128 (8 n) per
// lane, 32 lanes x 16B = 512B contiguous global store per f-row.
__global__ __launch_bounds__(256) void xt_build(
    const unsigned short* __restrict__ x_bf, unsigned short* __restrict__ xT) {
  __shared__ unsigned short tile[64 * 256];
  const int tid = threadIdx.x;
  const int n0 = blockIdx.x * 256;
  const int f0 = blockIdx.y * 64;
  const long long b = blockIdx.z;
  const unsigned short* xb = x_bf + b * 4194304LL;
  unsigned short* xTb = xT + b * 4194304LL;

  {  // phase 1
    const int c8 = (tid & 7) * 8;    // f-base; s(f)==c8 for f in [c8,c8+8)
    const int r  = tid >> 3;         // 0..31
#pragma unroll
    for (int rr = 0; rr < 8; ++rr) {
      int n = rr * 32 + r;
      bf16x8 v = *(const bf16x8*)&xb[(long long)(n0 + n) * 1024 + f0 + c8];
#pragma unroll
      for (int j = 0; j < 8; ++j)
        tile[(c8 + j) * 256 + (n ^ c8)] = (unsigned short)v[j];
    }
  }
  __syncthreads();
  {  // phase 2
    const int g    = tid & 31;       // n-chunk: 8 n per lane
    const int fgrp = tid >> 5;       // 0..7
#pragma unroll
    for (int it = 0; it < 8; ++it) {
      int f = it * 8 + fgrp;
      int s = ((f >> 3) & 7) * 8;
      bf16x8 v = *(const bf16x8*)&tile[f * 256 + ((g * 8) ^ s)];
      *(bf16x8*)&xTb[(long long)(f0 + f) * 4096 + n0 + g * 8] = v;
    }
  }
}

// ---- fused theta+phi gemm: one pass over x_bf, combined weights [512,1024] -
// grid (4,256): bx<2 -> Th[n,l] (normal);  bx>=2 -> PhT[l,n] via swapped-
// operand MFMA (first operand supplies C rows), coalesced along n.
__global__ __launch_bounds__(256) void gemm_qk(
    const unsigned short* __restrict__ X, const unsigned short* __restrict__ W,
    unsigned short* __restrict__ Th, unsigned short* __restrict__ PhT) {
  __shared__ unsigned short As[128 * 32];
  __shared__ unsigned short Bs[128 * 32];

  const int tid  = threadIdx.x;
  const int lane = tid & 63;
  const int wave = tid >> 6;
  int bx, by, bz;
  xcd_swizzle(bx, by, bz);
  (void)bz;
  const int m0 = by * 128;   // x rows
  const int n0 = bx * 128;   // combined weight rows (0..511)

  const int sub = lane >> 2;
  const int kk  = (lane & 3) * 8;
  const int wm = (wave >> 1) * 64;
  const int wn = (wave & 1) * 64;
  const int li = lane & 15;
  const int q  = lane >> 4;

  f32x4 acc[4][4] = {};

  for (int k0 = 0; k0 < 1024; k0 += 32) {
#pragma unroll
    for (int r = 0; r < 2; ++r) {
      int chunk = r * 4 + wave;
      int row = chunk * 16 + sub;
      gload_lds16(X + (long long)(m0 + row) * 1024 + k0 + kk, (char*)As + chunk * 1024);
      gload_lds16(W + (long long)(n0 + row) * 1024 + k0 + kk, (char*)Bs + chunk * 1024);
    }
    __syncthreads();
    bf16x8 af[4], bfr[4];
#pragma unroll
    for (int i = 0; i < 4; ++i) {
      af[i]  = *(const bf16x8*)&As[(wm + i * 16 + li) * 32 + q * 8];
      bfr[i] = *(const bf16x8*)&Bs[(wn + i * 16 + li) * 32 + q * 8];
    }
    if (bx < 2) {
#pragma unroll
      for (int i = 0; i < 4; ++i)
#pragma unroll
        for (int j = 0; j < 4; ++j)
          acc[i][j] = __builtin_amdgcn_mfma_f32_16x16x32_bf16(af[i], bfr[j], acc[i][j], 0, 0, 0);
    } else {
#pragma unroll
      for (int i = 0; i < 4; ++i)
#pragma unroll
        for (int j = 0; j < 4; ++j)
          acc[i][j] = __builtin_amdgcn_mfma_f32_16x16x32_bf16(bfr[i], af[j], acc[i][j], 0, 0, 0);
    }
    __syncthreads();
  }

  if (bx < 2) {
#pragma unroll
    for (int i = 0; i < 4; ++i)
#pragma unroll
      for (int j = 0; j < 4; ++j)
#pragma unroll
        for (int r = 0; r < 4; ++r) {
          int row = m0 + wm + i * 16 + q * 4 + r;       // n
          int col = n0 + wn + j * 16 + li;              // l (0..255)
          Th[(long long)row * 256 + col] = f32_to_bf16_rne(acc[i][j][r]);
        }
  } else {
    const int l0 = n0 - 256;
#pragma unroll
    for (int i = 0; i < 4; ++i)
#pragma unroll
      for (int j = 0; j < 4; ++j)
#pragma unroll
        for (int r = 0; r < 4; ++r) {
          int row = l0 + wn + i * 16 + q * 4 + r;       // l (0..255)
          int col = m0 + wm + j * 16 + li;              // n
          PhT[(long long)row * 32768 + col] = f32_to_bf16_rne(acc[i][j][r]);
        }
  }
}

// ---------------- C[M,N] = scale * A[M,K] @ B[N,K]^T (both K-contiguous) ----
template <bool OUT_F32>
__global__ __launch_bounds__(256) void gemm_bt(
    const unsigned short* __restrict__ A, const unsigned short* __restrict__ B,
    void* __restrict__ Cv,
    int K, int lda, int ldb, int ldc,
    long long sA, long long sB, long long sC, float scale) {
  __shared__ unsigned short As[128 * 32];
  __shared__ unsigned short Bs[128 * 32];

  const int tid  = threadIdx.x;
  const int lane = tid & 63;
  const int wave = tid >> 6;
  int bx, by, bz;
  xcd_swizzle(bx, by, bz);
  const int m0 = by * 128;
  const int n0 = bx * 128;
  const int z  = bz;

  A += (long long)z * sA;
  B += (long long)z * sB;

  const int sub = lane >> 2;
  const int kk  = (lane & 3) * 8;
  const int wm = (wave >> 1) * 64;
  const int wn = (wave & 1) * 64;
  const int li = lane & 15;
  const int q  = lane >> 4;

  f32x4 acc[4][4] = {};

  for (int k0 = 0; k0 < K; k0 += 32) {
#pragma unroll
    for (int r = 0; r < 2; ++r) {
      int chunk = r * 4 + wave;
      int row = chunk * 16 + sub;
      gload_lds16(A + (long long)(m0 + row) * lda + k0 + kk, (char*)As + chunk * 1024);
      gload_lds16(B + (long long)(n0 + row) * ldb + k0 + kk, (char*)Bs + chunk * 1024);
    }
    __syncthreads();
    bf16x8 af[4], bfr[4];
#pragma unroll
    for (int i = 0; i < 4; ++i) {
      af[i]  = *(const bf16x8*)&As[(wm + i * 16 + li) * 32 + q * 8];
      bfr[i] = *(const bf16x8*)&Bs[(wn + i * 16 + li) * 32 + q * 8];
    }
#pragma unroll
    for (int i = 0; i < 4; ++i)
#pragma unroll
      for (int j = 0; j < 4; ++j)
        acc[i][j] = __builtin_amdgcn_mfma_f32_16x16x32_bf16(af[i], bfr[j], acc[i][j], 0, 0, 0);
    __syncthreads();
  }

  if (OUT_F32) {
    float* C = (float*)Cv + (long long)z * sC;
#pragma unroll
    for (int i = 0; i < 4; ++i)
#pragma unroll
      for (int j = 0; j < 4; ++j)
#pragma unroll
        for (int r = 0; r < 4; ++r) {
          int row = m0 + wm + i * 16 + q * 4 + r;
          int col = n0 + wn + j * 16 + li;
          C[(long long)row * ldc + col] = acc[i][j][r] * scale;
        }
  } else {
    unsigned short* C = (unsigned short*)Cv + (long long)z * sC;
#pragma unroll
    for (int i = 0; i < 4; ++i)
#pragma unroll
      for (int j = 0; j < 4; ++j)
#pragma unroll
        for (int r = 0; r < 4; ++r) {
          int row = m0 + wm + i * 16 + q * 4 + r;
          int col = n0 + wn + j * 16 + li;
          C[(long long)row * ldc + col] = f32_to_bf16_rne(acc[i][j][r] * scale);
        }
  }
}

// ------------- split-K variant: fp32 partials, z = batch*nsplit + split -----
__global__ __launch_bounds__(256) void gemm_bt_split(
    const unsigned short* __restrict__ A, const unsigned short* __restrict__ B,
    float* __restrict__ Cp,
    int Ks, int lda, int ldb, int ldc,
    long long sA, long long sB, long long sC, int nsplit) {
  __shared__ unsigned short As[128 * 32];
  __shared__ unsigned short Bs[128 * 32];

  const int tid  = threadIdx.x;
  const int lane = tid & 63;
  const int wave = tid >> 6;
  int bx, by, bz;
  xcd_swizzle(bx, by, bz);
  const int m0 = by * 128;
  const int n0 = bx * 128;
  const int z  = bz;
  const int batch = z / nsplit;
  const int split = z - batch * nsplit;

  A += batch * sA + (long long)split * Ks;   // k-contiguous: split offsets along k
  B += batch * sB + (long long)split * Ks;
  Cp += (long long)z * sC;

  const int sub = lane >> 2;
  const int kk  = (lane & 3) * 8;
  const int wm = (wave >> 1) * 64;
  const int wn = (wave & 1) * 64;
  const int li = lane & 15;
  const int q  = lane >> 4;

  f32x4 acc[4][4] = {};

  for (int k0 = 0; k0 < Ks; k0 += 32) {
#pragma unroll
    for (int r = 0; r < 2; ++r) {
      int chunk = r * 4 + wave;
      int row = chunk * 16 + sub;
      gload_lds16(A + (long long)(m0 + row) * lda + k0 + kk, (char*)As + chunk * 1024);
      gload_lds16(B + (long long)(n0 + row) * ldb + k0 + kk, (char*)Bs + chunk * 1024);
    }
    __syncthreads();
    bf16x8 af[4], bfr[4];
#pragma unroll
    for (int i = 0; i < 4; ++i) {
      af[i]  = *(const bf16x8*)&As[(wm + i * 16 + li) * 32 + q * 8];
      bfr[i] = *(const bf16x8*)&Bs[(wn + i * 16 + li) * 32 + q * 8];
    }
#pragma unroll
    for (int i = 0; i < 4; ++i)
#pragma unroll
      for (int j = 0; j < 4; ++j)
        acc[i][j] = __builtin_amdgcn_mfma_f32_16x16x32_bf16(af[i], bfr[j], acc[i][j], 0, 0, 0);
    __syncthreads();
  }

#pragma unroll
  for (int i = 0; i < 4; ++i)
#pragma unroll
    for (int j = 0; j < 4; ++j)
#pragma unroll
      for (int r = 0; r < 4; ++r) {
        int row = m0 + wm + i * 16 + q * 4 + r;
        int col = n0 + wn + j * 16 + li;
        Cp[(long long)row * ldc + col] = acc[i][j][r];
      }
}

// ---- sum nsplit fp32 slices (each 262144 els per batch-slice) -> bf16 -----
__global__ __launch_bounds__(256) void reduce_splits(
    const float* __restrict__ P, unsigned short* __restrict__ O,
    int nsplit, float scale) {
  int i = (blockIdx.x * 256 + threadIdx.x) * 4;
  int batch = i >> 18;          // / 262144
  int j = i & 262143;
  const float* p = P + (long long)batch * nsplit * 262144 + j;
  float4 s = *(const float4*)p;
  for (int t = 1; t < nsplit; ++t) {
    float4 v = *(const float4*)(p + (long long)t * 262144);
    s.x += v.x; s.y += v.y; s.z += v.z; s.w += v.w;
  }
  ushort4 o;
  o.x = f32_to_bf16_rne(s.x * scale);
  o.y = f32_to_bf16_rne(s.y * scale);
  o.z = f32_to_bf16_rne(s.z * scale);
  o.w = f32_to_bf16_rne(s.w * scale);
  ((ushort4*)O)[i >> 2] = o;
}

// ---------------------------------------------------------------------------
extern "C" void kernel_launch(void* const* d_in, const int* in_sizes, int n_in,
                              void* d_out, int out_size, void* d_ws, size_t ws_size,
                              hipStream_t stream) {
  const float* x  = (const float*)d_in[0];   // [8,4096,1024]
  const float* Wt = (const float*)d_in[1];   // [256,1024]
  const float* Wp = (const float*)d_in[2];   // [256,1024]
  const float* Wg = (const float*)d_in[3];   // [1024,1024]
  float* out = (float*)d_out;                // [8,4096,1024] fp32 (128 MiB)

  // ws layout (<= 112,197,632 B proven):
  char* ws = (char*)d_ws;
  unsigned short* x_bf = (unsigned short*)(ws);               // 64 MB [32768,1024]
  unsigned short* Th   = (unsigned short*)(ws + 67108864);    // 16 MB theta [32768,256]
  unsigned short* PhT  = (unsigned short*)(ws + 83886080);    // 16 MB phiT [256,32768]
  unsigned short* Rt   = (unsigned short*)(ws + 100663296);   //  4 MB [8,256,1024]
  unsigned short* MT   = (unsigned short*)(ws + 104857600);   //  4 MB [8,1024,256]
  unsigned short* Wtb  = (unsigned short*)(ws + 109051904);   // 512 KB
  unsigned short* Wpb  = (unsigned short*)(ws + 109576192);   // 512 KB (contiguous after Wtb)
  unsigned short* Wgb  = (unsigned short*)(ws + 110100480);   //   2 MB

  // d_out as scratch until final gemm overwrites it:
  unsigned short* xT = (unsigned short*)d_out;              // [0,64MiB) [8,1024,4096]
  float* RtP = (float*)((char*)d_out + 67108864);           // [64,128MiB): 8 splits x 8 MiB

  cvt_all<<<dim3(3584), 256, 0, stream>>>(x, Wt, Wp, Wg, x_bf, Wtb, Wpb, Wgb);
  xt_build<<<dim3(16, 16, 8), 256, 0, stream>>>(x_bf, xT);

  // Th = x@Wt^T [32768,256] and PhT = (x@Wp^T)^T [256,32768]; W = [Wtb;Wpb]
  gemm_qk<<<dim3(4, 256, 1), 256, 0, stream>>>(x_bf, Wtb, Th, PhT);

  // Rt[b] = PhT_b @ xT_b^T : M=256 N=1024 K=4096, split-8 (Ks=512), 1024 blk
  gemm_bt_split<<<dim3(8, 2, 64), 256, 0, stream>>>(
      PhT, xT, RtP, 512, 32768, 4096, 1024,
      4096LL, 4194304LL, 262144LL, 8);
  reduce_splits<<<dim3(2048), 256, 0, stream>>>(RtP, Rt, 8, 1.0f);

  // MT[b] = scale * Wg @ Rt_b^T : M=1024 N=256 K=1024, unsplit, 128 blk
  gemm_bt<false><<<dim3(2, 8, 8), 256, 0, stream>>>(
      Wgb, Rt, MT, 1024, 1024, 1024, 256,
      0LL, 262144LL, 262144LL, 0.03125f);

  // out[b] = Th_b @ MT_b^T : M=4096 N=1024 K=256, fp32 out
  gemm_bt<true><<<dim3(8, 32, 8), 256, 0, stream>>>(
      Th, MT, out, 256, 256, 256, 1024,
      1048576LL, 262144LL, 4194304LL, 1.0f);
}

// Round 7
// 384.816 us; speedup vs baseline: 1.0554x; 1.0520x over previous
//
#include <hip/hip_runtime.h>
#include <hip/hip_bf16.h>
#include <stdint.h>

// Self-attention (no softmax) via matmul reassociation.
// R6: all gemms BK=32 -> BK=64 (half the barrier/drain events per K) with
//     rule-#21 LDS swizzle: linear global_load_lds dest + pre-swizzled global
//     source k-offset (kk = ((lane&7)^(lane>>3))*8) + XOR-swizzled reads
//     (slot = (q+ks*4) ^ (row&7)). Verified: bijective per row, post-swizzle
//     reads hit all 32 banks at 2 lanes/bank (free; old layout was 8-way).
//   cvt_all : x fp32 -> x_bf bf16 + all weights
//   xt_build: x_bf -> xT (transpose per batch, L3-hot src) [8,1024,4096]
//   gemm_qk : Th = x@Wt^T [32768,256] AND PhT = (x@Wp^T)^T [256,32768]
//   Rt      = PhT x xT^T (bt, K=4096 split-8)        [8,256,1024]
//   MT      = scale*Wg x Rt^T (bt, K=1024, unsplit)  [8,1024,256]
//   out     = Th x MT^T (bt, K=256, fp32 out)        [8,4096,1024]
// d_out doubles as scratch: xT [0,64MiB), RtP [64,128MiB).

typedef __attribute__((ext_vector_type(8))) short bf16x8;
typedef __attribute__((ext_vector_type(4))) float f32x4;

__device__ inline unsigned short f32_to_bf16_rne(float f) {
  union { float f; uint32_t u; } v; v.f = f;
  uint32_t r = v.u + 0x7fffu + ((v.u >> 16) & 1u);
  return (unsigned short)(r >> 16);
}

__device__ inline void gload_lds16(const void* g, void* lds) {
  __builtin_amdgcn_global_load_lds(
      (const __attribute__((address_space(1))) void*)g,
      (__attribute__((address_space(3))) void*)lds, 16, 0, 0);
}

// XCD-aware bijective remap of the flattened grid (requires total%8==0).
__device__ inline void xcd_swizzle(int& bx, int& by, int& bz) {
  int gx = gridDim.x, gy = gridDim.y;
  int total = gx * gy * gridDim.z;
  int lid = blockIdx.x + gx * (blockIdx.y + gy * blockIdx.z);
  int cpx = total >> 3;
  int swz = (lid & 7) * cpx + (lid >> 3);
  bx = swz % gx;
  int t = swz / gx;
  by = t % gy;
  bz = t / gy;
}

// ------- x fp32 -> x_bf bf16 (blocks 0..2047) + weights (blocks 2048..3583) --
__global__ __launch_bounds__(256) void cvt_all(
    const float* __restrict__ x, const float* __restrict__ Wt,
    const float* __restrict__ Wp, const float* __restrict__ Wg,
    unsigned short* __restrict__ x_bf, unsigned short* __restrict__ Wtb,
    unsigned short* __restrict__ Wpb, unsigned short* __restrict__ Wgb) {
  int bid = blockIdx.x;
  if (bid < 2048) {
    long long idx = (long long)bid * 256 + threadIdx.x;
    const long long stride = 2048LL * 256LL;
#pragma unroll 2
    for (long long i = idx; i < 4194304LL; i += stride) {
      float4 a = ((const float4*)x)[i * 2];
      float4 b = ((const float4*)x)[i * 2 + 1];
      bf16x8 o;
      o[0] = (short)f32_to_bf16_rne(a.x);
      o[1] = (short)f32_to_bf16_rne(a.y);
      o[2] = (short)f32_to_bf16_rne(a.z);
      o[3] = (short)f32_to_bf16_rne(a.w);
      o[4] = (short)f32_to_bf16_rne(b.x);
      o[5] = (short)f32_to_bf16_rne(b.y);
      o[6] = (short)f32_to_bf16_rne(b.z);
      o[7] = (short)f32_to_bf16_rne(b.w);
      ((bf16x8*)x_bf)[i] = o;
    }
  } else {
    int i = (bid - 2048) * 256 + threadIdx.x;  // float4 index, total 393216
    const float* src;
    unsigned short* dst;
    int off;
    if (i < 65536) { src = Wt; dst = Wtb; off = i; }
    else if (i < 131072) { src = Wp; dst = Wpb; off = i - 65536; }
    else { src = Wg; dst = Wgb; off = i - 131072; }
    float4 v = ((const float4*)src)[off];
    ushort4 o;
    o.x = f32_to_bf16_rne(v.x);
    o.y = f32_to_bf16_rne(v.y);
    o.z = f32_to_bf16_rne(v.z);
    o.w = f32_to_bf16_rne(v.w);
    ((ushort4*)dst)[off] = o;
  }
}

// ------------- transpose x_bf -> xT, 256n x 64f tile through LDS -----------
// LDS tile[f][n] (64x256) with n-swizzle n ^ s(f), s(f)=((f>>3)&7)*8.
__global__ __launch_bounds__(256) void xt_build(
    const unsigned short* __restrict__ x_bf, unsigned short* __restrict__ xT) {
  __shared__ unsigned short tile[64 * 256];
  const int tid = threadIdx.x;
  const int n0 = blockIdx.x * 256;
  const int f0 = blockIdx.y * 64;
  const long long b = blockIdx.z;
  const unsigned short* xb = x_bf + b * 4194304LL;
  unsigned short* xTb = xT + b * 4194304LL;

  {  // phase 1
    const int c8 = (tid & 7) * 8;    // f-base; s(f)==c8 for f in [c8,c8+8)
    const int r  = tid >> 3;         // 0..31
#pragma unroll
    for (int rr = 0; rr < 8; ++rr) {
      int n = rr * 32 + r;
      bf16x8 v = *(const bf16x8*)&xb[(long long)(n0 + n) * 1024 + f0 + c8];
#pragma unroll
      for (int j = 0; j < 8; ++j)
        tile[(c8 + j) * 256 + (n ^ c8)] = (unsigned short)v[j];
    }
  }
  __syncthreads();
  {  // phase 2
    const int g    = tid & 31;       // n-chunk: 8 n per lane
    const int fgrp = tid >> 5;       // 0..7
#pragma unroll
    for (int it = 0; it < 8; ++it) {
      int f = it * 8 + fgrp;
      int s = ((f >> 3) & 7) * 8;
      bf16x8 v = *(const bf16x8*)&tile[f * 256 + ((g * 8) ^ s)];
      *(bf16x8*)&xTb[(long long)(f0 + f) * 4096 + n0 + g * 8] = v;
    }
  }
}

// ---- fused theta+phi gemm: one pass over x_bf, combined weights [512,1024] -
// BK=64, swizzled LDS (see header). grid (4,256): bx<2 -> Th; bx>=2 -> PhT
// via swapped-operand MFMA.
__global__ __launch_bounds__(256) void gemm_qk(
    const unsigned short* __restrict__ X, const unsigned short* __restrict__ W,
    unsigned short* __restrict__ Th, unsigned short* __restrict__ PhT) {
  __shared__ unsigned short As[128 * 64];
  __shared__ unsigned short Bs[128 * 64];

  const int tid  = threadIdx.x;
  const int lane = tid & 63;
  const int wave = tid >> 6;
  int bx, by, bz;
  xcd_swizzle(bx, by, bz);
  (void)bz;
  const int m0 = by * 128;   // x rows
  const int n0 = bx * 128;   // combined weight rows (0..511)

  const int sub8 = lane >> 3;                       // row within 8-row chunk
  const int kx   = ((lane & 7) ^ (lane >> 3)) * 8;  // pre-swizzled k-offset
  const int wm = (wave >> 1) * 64;
  const int wn = (wave & 1) * 64;
  const int li = lane & 15;
  const int q  = lane >> 4;
  const int l7 = li & 7;

  f32x4 acc[4][4] = {};

  for (int k0 = 0; k0 < 1024; k0 += 64) {
#pragma unroll
    for (int r = 0; r < 4; ++r) {
      int chunk = r * 4 + wave;           // 0..15
      int row = chunk * 8 + sub8;         // 0..127
      gload_lds16(X + (long long)(m0 + row) * 1024 + k0 + kx, (char*)As + chunk * 1024);
      gload_lds16(W + (long long)(n0 + row) * 1024 + k0 + kx, (char*)Bs + chunk * 1024);
    }
    __syncthreads();
#pragma unroll
    for (int ks = 0; ks < 2; ++ks) {
      const int sl = ((q + ks * 4) ^ l7) << 4;
      bf16x8 af[4], bfr[4];
#pragma unroll
      for (int i = 0; i < 4; ++i) {
        af[i]  = *(const bf16x8*)((const char*)As + ((wm + i * 16 + li) << 7) + sl);
        bfr[i] = *(const bf16x8*)((const char*)Bs + ((wn + i * 16 + li) << 7) + sl);
      }
      if (bx < 2) {
#pragma unroll
        for (int i = 0; i < 4; ++i)
#pragma unroll
          for (int j = 0; j < 4; ++j)
            acc[i][j] = __builtin_amdgcn_mfma_f32_16x16x32_bf16(af[i], bfr[j], acc[i][j], 0, 0, 0);
      } else {
#pragma unroll
        for (int i = 0; i < 4; ++i)
#pragma unroll
          for (int j = 0; j < 4; ++j)
            acc[i][j] = __builtin_amdgcn_mfma_f32_16x16x32_bf16(bfr[i], af[j], acc[i][j], 0, 0, 0);
      }
    }
    __syncthreads();
  }

  if (bx < 2) {
#pragma unroll
    for (int i = 0; i < 4; ++i)
#pragma unroll
      for (int j = 0; j < 4; ++j)
#pragma unroll
        for (int r = 0; r < 4; ++r) {
          int row = m0 + wm + i * 16 + q * 4 + r;       // n
          int col = n0 + wn + j * 16 + li;              // l (0..255)
          Th[(long long)row * 256 + col] = f32_to_bf16_rne(acc[i][j][r]);
        }
  } else {
    const int l0 = n0 - 256;
#pragma unroll
    for (int i = 0; i < 4; ++i)
#pragma unroll
      for (int j = 0; j < 4; ++j)
#pragma unroll
        for (int r = 0; r < 4; ++r) {
          int row = l0 + wn + i * 16 + q * 4 + r;       // l (0..255)
          int col = m0 + wm + j * 16 + li;              // n
          PhT[(long long)row * 32768 + col] = f32_to_bf16_rne(acc[i][j][r]);
        }
  }
}

// ---------------- C[M,N] = scale * A[M,K] @ B[N,K]^T (both K-contiguous) ----
// BK=64 swizzled (see header). K must be a multiple of 64.
template <bool OUT_F32>
__global__ __launch_bounds__(256) void gemm_bt(
    const unsigned short* __restrict__ A, const unsigned short* __restrict__ B,
    void* __restrict__ Cv,
    int K, int lda, int ldb, int ldc,
    long long sA, long long sB, long long sC, float scale) {
  __shared__ unsigned short As[128 * 64];
  __shared__ unsigned short Bs[128 * 64];

  const int tid  = threadIdx.x;
  const int lane = tid & 63;
  const int wave = tid >> 6;
  int bx, by, bz;
  xcd_swizzle(bx, by, bz);
  const int m0 = by * 128;
  const int n0 = bx * 128;
  const int z  = bz;

  A += (long long)z * sA;
  B += (long long)z * sB;

  const int sub8 = lane >> 3;
  const int kx   = ((lane & 7) ^ (lane >> 3)) * 8;
  const int wm = (wave >> 1) * 64;
  const int wn = (wave & 1) * 64;
  const int li = lane & 15;
  const int q  = lane >> 4;
  const int l7 = li & 7;

  f32x4 acc[4][4] = {};

  for (int k0 = 0; k0 < K; k0 += 64) {
#pragma unroll
    for (int r = 0; r < 4; ++r) {
      int chunk = r * 4 + wave;
      int row = chunk * 8 + sub8;
      gload_lds16(A + (long long)(m0 + row) * lda + k0 + kx, (char*)As + chunk * 1024);
      gload_lds16(B + (long long)(n0 + row) * ldb + k0 + kx, (char*)Bs + chunk * 1024);
    }
    __syncthreads();
#pragma unroll
    for (int ks = 0; ks < 2; ++ks) {
      const int sl = ((q + ks * 4) ^ l7) << 4;
      bf16x8 af[4], bfr[4];
#pragma unroll
      for (int i = 0; i < 4; ++i) {
        af[i]  = *(const bf16x8*)((const char*)As + ((wm + i * 16 + li) << 7) + sl);
        bfr[i] = *(const bf16x8*)((const char*)Bs + ((wn + i * 16 + li) << 7) + sl);
      }
#pragma unroll
      for (int i = 0; i < 4; ++i)
#pragma unroll
        for (int j = 0; j < 4; ++j)
          acc[i][j] = __builtin_amdgcn_mfma_f32_16x16x32_bf16(af[i], bfr[j], acc[i][j], 0, 0, 0);
    }
    __syncthreads();
  }

  if (OUT_F32) {
    float* C = (float*)Cv + (long long)z * sC;
#pragma unroll
    for (int i = 0; i < 4; ++i)
#pragma unroll
      for (int j = 0; j < 4; ++j)
#pragma unroll
        for (int r = 0; r < 4; ++r) {
          int row = m0 + wm + i * 16 + q * 4 + r;
          int col = n0 + wn + j * 16 + li;
          C[(long long)row * ldc + col] = acc[i][j][r] * scale;
        }
  } else {
    unsigned short* C = (unsigned short*)Cv + (long long)z * sC;
#pragma unroll
    for (int i = 0; i < 4; ++i)
#pragma unroll
      for (int j = 0; j < 4; ++j)
#pragma unroll
        for (int r = 0; r < 4; ++r) {
          int row = m0 + wm + i * 16 + q * 4 + r;
          int col = n0 + wn + j * 16 + li;
          C[(long long)row * ldc + col] = f32_to_bf16_rne(acc[i][j][r] * scale);
        }
  }
}

// ------------- split-K variant: fp32 partials, z = batch*nsplit + split -----
// BK=64 swizzled. Ks must be a multiple of 64.
__global__ __launch_bounds__(256) void gemm_bt_split(
    const unsigned short* __restrict__ A, const unsigned short* __restrict__ B,
    float* __restrict__ Cp,
    int Ks, int lda, int ldb, int ldc,
    long long sA, long long sB, long long sC, int nsplit) {
  __shared__ unsigned short As[128 * 64];
  __shared__ unsigned short Bs[128 * 64];

  const int tid  = threadIdx.x;
  const int lane = tid & 63;
  const int wave = tid >> 6;
  int bx, by, bz;
  xcd_swizzle(bx, by, bz);
  const int m0 = by * 128;
  const int n0 = bx * 128;
  const int z  = bz;
  const int batch = z / nsplit;
  const int split = z - batch * nsplit;

  A += batch * sA + (long long)split * Ks;   // k-contiguous: split offsets along k
  B += batch * sB + (long long)split * Ks;
  Cp += (long long)z * sC;

  const int sub8 = lane >> 3;
  const int kx   = ((lane & 7) ^ (lane >> 3)) * 8;
  const int wm = (wave >> 1) * 64;
  const int wn = (wave & 1) * 64;
  const int li = lane & 15;
  const int q  = lane >> 4;
  const int l7 = li & 7;

  f32x4 acc[4][4] = {};

  for (int k0 = 0; k0 < Ks; k0 += 64) {
#pragma unroll
    for (int r = 0; r < 4; ++r) {
      int chunk = r * 4 + wave;
      int row = chunk * 8 + sub8;
      gload_lds16(A + (long long)(m0 + row) * lda + k0 + kx, (char*)As + chunk * 1024);
      gload_lds16(B + (long long)(n0 + row) * ldb + k0 + kx, (char*)Bs + chunk * 1024);
    }
    __syncthreads();
#pragma unroll
    for (int ks = 0; ks < 2; ++ks) {
      const int sl = ((q + ks * 4) ^ l7) << 4;
      bf16x8 af[4], bfr[4];
#pragma unroll
      for (int i = 0; i < 4; ++i) {
        af[i]  = *(const bf16x8*)((const char*)As + ((wm + i * 16 + li) << 7) + sl);
        bfr[i] = *(const bf16x8*)((const char*)Bs + ((wn + i * 16 + li) << 7) + sl);
      }
#pragma unroll
      for (int i = 0; i < 4; ++i)
#pragma unroll
        for (int j = 0; j < 4; ++j)
          acc[i][j] = __builtin_amdgcn_mfma_f32_16x16x32_bf16(af[i], bfr[j], acc[i][j], 0, 0, 0);
    }
    __syncthreads();
  }

#pragma unroll
  for (int i = 0; i < 4; ++i)
#pragma unroll
    for (int j = 0; j < 4; ++j)
#pragma unroll
      for (int r = 0; r < 4; ++r) {
        int row = m0 + wm + i * 16 + q * 4 + r;
        int col = n0 + wn + j * 16 + li;
        Cp[(long long)row * ldc + col] = acc[i][j][r];
      }
}

// ---- sum nsplit fp32 slices (each 262144 els per batch-slice) -> bf16 -----
__global__ __launch_bounds__(256) void reduce_splits(
    const float* __restrict__ P, unsigned short* __restrict__ O,
    int nsplit, float scale) {
  int i = (blockIdx.x * 256 + threadIdx.x) * 4;
  int batch = i >> 18;          // / 262144
  int j = i & 262143;
  const float* p = P + (long long)batch * nsplit * 262144 + j;
  float4 s = *(const float4*)p;
  for (int t = 1; t < nsplit; ++t) {
    float4 v = *(const float4*)(p + (long long)t * 262144);
    s.x += v.x; s.y += v.y; s.z += v.z; s.w += v.w;
  }
  ushort4 o;
  o.x = f32_to_bf16_rne(s.x * scale);
  o.y = f32_to_bf16_rne(s.y * scale);
  o.z = f32_to_bf16_rne(s.z * scale);
  o.w = f32_to_bf16_rne(s.w * scale);
  ((ushort4*)O)[i >> 2] = o;
}

// ---------------------------------------------------------------------------
extern "C" void kernel_launch(void* const* d_in, const int* in_sizes, int n_in,
                              void* d_out, int out_size, void* d_ws, size_t ws_size,
                              hipStream_t stream) {
  const float* x  = (const float*)d_in[0];   // [8,4096,1024]
  const float* Wt = (const float*)d_in[1];   // [256,1024]
  const float* Wp = (const float*)d_in[2];   // [256,1024]
  const float* Wg = (const float*)d_in[3];   // [1024,1024]
  float* out = (float*)d_out;                // [8,4096,1024] fp32 (128 MiB)

  // ws layout (<= 112,197,632 B proven):
  char* ws = (char*)d_ws;
  unsigned short* x_bf = (unsigned short*)(ws);               // 64 MB [32768,1024]
  unsigned short* Th   = (unsigned short*)(ws + 67108864);    // 16 MB theta [32768,256]
  unsigned short* PhT  = (unsigned short*)(ws + 83886080);    // 16 MB phiT [256,32768]
  unsigned short* Rt   = (unsigned short*)(ws + 100663296);   //  4 MB [8,256,1024]
  unsigned short* MT   = (unsigned short*)(ws + 104857600);   //  4 MB [8,1024,256]
  unsigned short* Wtb  = (unsigned short*)(ws + 109051904);   // 512 KB
  unsigned short* Wpb  = (unsigned short*)(ws + 109576192);   // 512 KB (contiguous after Wtb)
  unsigned short* Wgb  = (unsigned short*)(ws + 110100480);   //   2 MB

  // d_out as scratch until final gemm overwrites it:
  unsigned short* xT = (unsigned short*)d_out;              // [0,64MiB) [8,1024,4096]
  float* RtP = (float*)((char*)d_out + 67108864);           // [64,128MiB): 8 splits x 8 MiB

  cvt_all<<<dim3(3584), 256, 0, stream>>>(x, Wt, Wp, Wg, x_bf, Wtb, Wpb, Wgb);
  xt_build<<<dim3(16, 16, 8), 256, 0, stream>>>(x_bf, xT);

  // Th = x@Wt^T [32768,256] and PhT = (x@Wp^T)^T [256,32768]; W = [Wtb;Wpb]
  gemm_qk<<<dim3(4, 256, 1), 256, 0, stream>>>(x_bf, Wtb, Th, PhT);

  // Rt[b] = PhT_b @ xT_b^T : M=256 N=1024 K=4096, split-8 (Ks=512), 1024 blk
  gemm_bt_split<<<dim3(8, 2, 64), 256, 0, stream>>>(
      PhT, xT, RtP, 512, 32768, 4096, 1024,
      4096LL, 4194304LL, 262144LL, 8);
  reduce_splits<<<dim3(2048), 256, 0, stream>>>(RtP, Rt, 8, 1.0f);

  // MT[b] = scale * Wg @ Rt_b^T : M=1024 N=256 K=1024, unsplit, 128 blk
  gemm_bt<false><<<dim3(2, 8, 8), 256, 0, stream>>>(
      Wgb, Rt, MT, 1024, 1024, 1024, 256,
      0LL, 262144LL, 262144LL, 0.03125f);

  // out[b] = Th_b @ MT_b^T : M=4096 N=1024 K=256, fp32 out
  gemm_bt<true><<<dim3(8, 32, 8), 256, 0, stream>>>(
      Th, MT, out, 256, 256, 256, 1024,
      1048576LL, 262144LL, 4194304LL, 1.0f);
}